// Round 1
// baseline (661.951 us; speedup 1.0000x reference)
//
#include <hip/hip_runtime.h>
#include <hip/hip_bf16.h>

#define S_LEN  2048
#define BATCH  2
#define DMODEL 1024
#define NHEAD  16
#define DHEAD  64
#define DFF    4096
#define NTOK   (BATCH * S_LEN)

typedef __attribute__((ext_vector_type(8))) short short8;
typedef __attribute__((ext_vector_type(4))) short short4v;
typedef __attribute__((ext_vector_type(4))) float f32x4;

__device__ __forceinline__ short f2bs(float f) {
  __hip_bfloat16 h = __float2bfloat16(f);
  short s;
  __builtin_memcpy(&s, &h, sizeof(short));
  return s;
}

__device__ __forceinline__ f32x4 mfma16(short8 a, short8 b, f32x4 c) {
  return __builtin_amdgcn_mfma_f32_16x16x32_bf16(a, b, c, 0, 0, 0);
}

// ---------------------------------------------------------------------------
// Weight transpose + cast: in f32 [R][C] -> out bf16 [C][R]
// ---------------------------------------------------------------------------
__global__ void transpose_cast(const float* __restrict__ in, short* __restrict__ out,
                               int R, int C) {
  __shared__ float tile[32][33];
  const int c0 = blockIdx.x * 32, r0 = blockIdx.y * 32;
  const int tx = threadIdx.x, ty = threadIdx.y;  // 32 x 8
#pragma unroll
  for (int i = 0; i < 32; i += 8)
    tile[ty + i][tx] = in[(size_t)(r0 + ty + i) * C + c0 + tx];
  __syncthreads();
#pragma unroll
  for (int i = 0; i < 32; i += 8)
    out[(size_t)(c0 + ty + i) * R + r0 + tx] = f2bs(tile[tx][ty + i]);
}

// ---------------------------------------------------------------------------
// Token prep: qkb = bf16(src+pos), srcb = bf16(src)
// ---------------------------------------------------------------------------
__global__ void prep_tokens(const float* __restrict__ src, const float* __restrict__ pos,
                            short* __restrict__ qkb, short* __restrict__ srcb) {
  const int i = (blockIdx.x * blockDim.x + threadIdx.x) * 4;
  float4 s = *(const float4*)(src + i);
  float4 p = *(const float4*)(pos + i);
  short4v q4 = {f2bs(s.x + p.x), f2bs(s.y + p.y), f2bs(s.z + p.z), f2bs(s.w + p.w)};
  short4v s4 = {f2bs(s.x), f2bs(s.y), f2bs(s.z), f2bs(s.w)};
  *(short4v*)(qkb + i) = q4;
  *(short4v*)(srcb + i) = s4;
}

// ---------------------------------------------------------------------------
// GEMM: C[M][N] = A[M][K](bf16) @ Bt[N][K](bf16)^T + bias, optional ReLU.
// 128x128 tile, BK=32, 256 threads (4 waves, each 64x64 = 4x4 MFMA tiles).
// ---------------------------------------------------------------------------
template <int RELU, int OUT_BF16>
__global__ __launch_bounds__(256) void gemm_bt(
    const short* __restrict__ A, const short* __restrict__ Bt,
    const float* __restrict__ bias, float* __restrict__ Cf, short* __restrict__ Cb,
    int M, int N, int K) {
  __shared__ __attribute__((aligned(16))) short As[128][40];
  __shared__ __attribute__((aligned(16))) short Bs[128][40];

  const int tid = threadIdx.x;
  const int wave = tid >> 6, lane = tid & 63;
  const int lm = lane & 15, lq = lane >> 4;
  const int row0 = blockIdx.y * 128, col0 = blockIdx.x * 128;
  const int wr = (wave >> 1) * 64, wc = (wave & 1) * 64;

  const int lr = tid >> 2;          // 0..63 staging row
  const int lc8 = (tid & 3) * 8;    // 0,8,16,24 staging col

  f32x4 acc[4][4];
#pragma unroll
  for (int i = 0; i < 4; i++)
#pragma unroll
    for (int j = 0; j < 4; j++) acc[i][j] = (f32x4){0.f, 0.f, 0.f, 0.f};

  for (int k0 = 0; k0 < K; k0 += 32) {
    const short* ap = A + (size_t)(row0 + lr) * K + k0 + lc8;
    *(int4*)(&As[lr][lc8]) = *(const int4*)ap;
    *(int4*)(&As[lr + 64][lc8]) = *(const int4*)(ap + (size_t)64 * K);
    const short* bp = Bt + (size_t)(col0 + lr) * K + k0 + lc8;
    *(int4*)(&Bs[lr][lc8]) = *(const int4*)bp;
    *(int4*)(&Bs[lr + 64][lc8]) = *(const int4*)(bp + (size_t)64 * K);
    __syncthreads();

    short8 af[4], bfr[4];
#pragma unroll
    for (int i = 0; i < 4; i++) af[i] = *(const short8*)(&As[wr + 16 * i + lm][lq * 8]);
#pragma unroll
    for (int j = 0; j < 4; j++) bfr[j] = *(const short8*)(&Bs[wc + 16 * j + lm][lq * 8]);
#pragma unroll
    for (int i = 0; i < 4; i++)
#pragma unroll
      for (int j = 0; j < 4; j++) acc[i][j] = mfma16(af[i], bfr[j], acc[i][j]);
    __syncthreads();
  }

#pragma unroll
  for (int i = 0; i < 4; i++) {
#pragma unroll
    for (int j = 0; j < 4; j++) {
      const int col = col0 + wc + 16 * j + lm;
      const float bs = bias[col];
#pragma unroll
      for (int r = 0; r < 4; r++) {
        const int row = row0 + wr + 16 * i + lq * 4 + r;
        float v = acc[i][j][r] + bs;
        if (RELU) v = fmaxf(v, 0.f);
        if (OUT_BF16)
          Cb[(size_t)row * N + col] = f2bs(v);
        else
          Cf[(size_t)row * N + col] = v;
      }
    }
  }
}

// ---------------------------------------------------------------------------
// Fused attention: per block = (64 queries, head h, batch b). 4 waves x 16 q.
// scores = Q K^T / 8 + corr, online softmax, O = P V. Q/K/V: [NTOK][DMODEL] bf16.
// ---------------------------------------------------------------------------
__global__ __launch_bounds__(256) void attn_kernel(
    const short* __restrict__ Q, const short* __restrict__ K,
    const short* __restrict__ V, const float* __restrict__ corr,
    short* __restrict__ ctx) {
  const int qtile = blockIdx.x, h = blockIdx.y, b = blockIdx.z;
  const int tid = threadIdx.x;
  const int wave = tid >> 6, lane = tid & 63;
  const int lm = lane & 15, lq = lane >> 4;
  const int wq = qtile * 64 + wave * 16;  // this wave's query base (0..2047)

  __shared__ __attribute__((aligned(16))) short Ks[32][72];      // [key][dk]
  __shared__ __attribute__((aligned(16))) short Vt[64][40];      // [dk][key]
  __shared__ __attribute__((aligned(16))) short Ps[4][16][40];   // per-wave P

  // Q A-fragments (rows wq+lm, k = lq*8.., held for whole kernel)
  const short* qrow = Q + (size_t)(b * S_LEN + wq + lm) * DMODEL + h * DHEAD;
  const short8 qa0 = *(const short8*)(qrow + lq * 8);
  const short8 qa1 = *(const short8*)(qrow + lq * 8 + 32);

  f32x4 o[4];
#pragma unroll
  for (int c = 0; c < 4; c++) o[c] = (f32x4){0.f, 0.f, 0.f, 0.f};
  float mrow[4], lrow[4];
#pragma unroll
  for (int r = 0; r < 4; r++) { mrow[r] = -1e30f; lrow[r] = 0.f; }

  const int ckey = tid >> 3;        // 0..31 cooperative-load key
  const int cc8 = (tid & 7) * 8;    // 0..56 cooperative-load dim

  for (int kt = 0; kt < S_LEN; kt += 32) {
    // --- cooperative stage: K tile [32][64], V tile transposed [64][32]
    const short* kp = K + (size_t)(b * S_LEN + kt + ckey) * DMODEL + h * DHEAD + cc8;
    *(int4*)(&Ks[ckey][cc8]) = *(const int4*)kp;
    const short* vp = V + (size_t)(b * S_LEN + kt + ckey) * DMODEL + h * DHEAD + cc8;
    short8 vv = *(const short8*)vp;
#pragma unroll
    for (int j = 0; j < 8; j++) Vt[cc8 + j][ckey] = vv[j];
    __syncthreads();

    // --- scores: 16 queries x 32 keys (two 16-col tiles)
    f32x4 s[2];
#pragma unroll
    for (int t = 0; t < 2; t++) {
      short8 kb0 = *(const short8*)(&Ks[t * 16 + lm][lq * 8]);
      short8 kb1 = *(const short8*)(&Ks[t * 16 + lm][lq * 8 + 32]);
      f32x4 a = (f32x4){0.f, 0.f, 0.f, 0.f};
      a = mfma16(qa0, kb0, a);
      a = mfma16(qa1, kb1, a);
      s[t] = a;
    }

    // --- scale + corr bias + online softmax
#pragma unroll
    for (int r = 0; r < 4; r++) {
      const int qg = wq + lq * 4 + r;
      const size_t cb = ((size_t)b * S_LEN + qg) * S_LEN + kt;
      const float c0 = corr[cb + lm];
      const float c1 = corr[cb + 16 + lm];
      float s0 = s[0][r] * 0.125f + c0;
      float s1 = s[1][r] * 0.125f + c1;
      float v = fmaxf(s0, s1);
#pragma unroll
      for (int off = 1; off < 16; off <<= 1) v = fmaxf(v, __shfl_xor(v, off));
      const float mo = mrow[r];
      const float mn = fmaxf(mo, v);
      const float alpha = __expf(mo - mn);
      const float p0 = __expf(s0 - mn);
      const float p1 = __expf(s1 - mn);
      float rs = p0 + p1;
#pragma unroll
      for (int off = 1; off < 16; off <<= 1) rs += __shfl_xor(rs, off);
      lrow[r] = lrow[r] * alpha + rs;
      mrow[r] = mn;
#pragma unroll
      for (int c = 0; c < 4; c++) o[c][r] *= alpha;
      Ps[wave][lq * 4 + r][lm] = f2bs(p0);
      Ps[wave][lq * 4 + r][lm + 16] = f2bs(p1);
    }

    // --- P (A-layout) @ V: contraction over 32 keys in one MFMA
    const short8 pa = *(const short8*)(&Ps[wave][lm][lq * 8]);
#pragma unroll
    for (int c = 0; c < 4; c++) {
      short8 vb = *(const short8*)(&Vt[c * 16 + lm][lq * 8]);
      o[c] = mfma16(pa, vb, o[c]);
    }
    __syncthreads();
  }

  // --- epilogue: O / l, write ctx[token][h*64 + d] (bf16)
#pragma unroll
  for (int r = 0; r < 4; r++) {
    const float inv = 1.0f / lrow[r];
    short* cp = ctx + (size_t)(b * S_LEN + wq + lq * 4 + r) * DMODEL + h * DHEAD;
#pragma unroll
    for (int c = 0; c < 4; c++) cp[c * 16 + lm] = f2bs(o[c][r] * inv);
  }
}

// ---------------------------------------------------------------------------
// Residual + LayerNorm over 1024 dims. One block (256 thr) per token row.
// ---------------------------------------------------------------------------
__global__ __launch_bounds__(256) void residual_ln(
    const float* __restrict__ xa, const float* __restrict__ xb,
    const float* __restrict__ g, const float* __restrict__ be,
    float* __restrict__ outf, short* __restrict__ outb) {
  const int row = blockIdx.x;
  const int t = threadIdx.x;
  const size_t base = (size_t)row * DMODEL + t * 4;
  float4 a = *(const float4*)(xa + base);
  float4 b = *(const float4*)(xb + base);
  const float v0 = a.x + b.x, v1 = a.y + b.y, v2 = a.z + b.z, v3 = a.w + b.w;
  float sum = v0 + v1 + v2 + v3;
  float sq = v0 * v0 + v1 * v1 + v2 * v2 + v3 * v3;
#pragma unroll
  for (int off = 1; off < 64; off <<= 1) {
    sum += __shfl_xor(sum, off);
    sq += __shfl_xor(sq, off);
  }
  __shared__ float ssum[4], ssq[4];
  const int wave = t >> 6;
  if ((t & 63) == 0) { ssum[wave] = sum; ssq[wave] = sq; }
  __syncthreads();
  sum = ssum[0] + ssum[1] + ssum[2] + ssum[3];
  sq = ssq[0] + ssq[1] + ssq[2] + ssq[3];
  const float mean = sum * (1.0f / DMODEL);
  const float var = sq * (1.0f / DMODEL) - mean * mean;
  const float rstd = rsqrtf(var + 1e-5f);
  float4 gv = *(const float4*)(g + t * 4);
  float4 bv = *(const float4*)(be + t * 4);
  const float o0 = (v0 - mean) * rstd * gv.x + bv.x;
  const float o1 = (v1 - mean) * rstd * gv.y + bv.y;
  const float o2 = (v2 - mean) * rstd * gv.z + bv.z;
  const float o3 = (v3 - mean) * rstd * gv.w + bv.w;
  if (outf) {
    float4 ov = {o0, o1, o2, o3};
    *(float4*)(outf + base) = ov;
  }
  if (outb) {
    short4v ob = {f2bs(o0), f2bs(o1), f2bs(o2), f2bs(o3)};
    *(short4v*)(outb + base) = ob;
  }
}

// ---------------------------------------------------------------------------
extern "C" void kernel_launch(void* const* d_in, const int* in_sizes, int n_in,
                              void* d_out, int out_size, void* d_ws, size_t ws_size,
                              hipStream_t stream) {
  const float* src = (const float*)d_in[0];
  const float* corr = (const float*)d_in[1];
  const float* pos = (const float*)d_in[2];
  const float* Wq = (const float*)d_in[3];
  const float* bq = (const float*)d_in[4];
  const float* Wk = (const float*)d_in[5];
  const float* bk = (const float*)d_in[6];
  const float* Wv = (const float*)d_in[7];
  const float* bv = (const float*)d_in[8];
  const float* Wo = (const float*)d_in[9];
  const float* bo = (const float*)d_in[10];
  const float* W1 = (const float*)d_in[11];
  const float* b1 = (const float*)d_in[12];
  const float* W2 = (const float*)d_in[13];
  const float* b2 = (const float*)d_in[14];
  const float* g1 = (const float*)d_in[15];
  const float* be1 = (const float*)d_in[16];
  const float* g2 = (const float*)d_in[17];
  const float* be2 = (const float*)d_in[18];
  float* out = (float*)d_out;

  char* ws = (char*)d_ws;
  size_t off = 0;
  auto alloc = [&](size_t bytes) {
    char* p = ws + off;
    off += (bytes + 255) & ~(size_t)255;
    return p;
  };
  short* WqT = (short*)alloc((size_t)DMODEL * DMODEL * 2);
  short* WkT = (short*)alloc((size_t)DMODEL * DMODEL * 2);
  short* WvT = (short*)alloc((size_t)DMODEL * DMODEL * 2);
  short* WoT = (short*)alloc((size_t)DMODEL * DMODEL * 2);
  short* W1T = (short*)alloc((size_t)DFF * DMODEL * 2);    // [4096][1024]
  short* W2T = (short*)alloc((size_t)DMODEL * DFF * 2);    // [1024][4096]
  short* qkb = (short*)alloc((size_t)NTOK * DMODEL * 2);
  short* srcb = (short*)alloc((size_t)NTOK * DMODEL * 2);
  short* Qb = (short*)alloc((size_t)NTOK * DMODEL * 2);
  short* Kb = (short*)alloc((size_t)NTOK * DMODEL * 2);
  short* Vb = (short*)alloc((size_t)NTOK * DMODEL * 2);
  short* ctxb = (short*)alloc((size_t)NTOK * DMODEL * 2);
  float* attn_out = (float*)alloc((size_t)NTOK * DMODEL * 4);
  float* x1f = (float*)alloc((size_t)NTOK * DMODEL * 4);
  short* x1b = (short*)alloc((size_t)NTOK * DMODEL * 2);
  short* Hb = (short*)alloc((size_t)NTOK * DFF * 2);
  float* Yf = (float*)alloc((size_t)NTOK * DMODEL * 4);

  const dim3 tb(32, 8);
  transpose_cast<<<dim3(32, 32), tb, 0, stream>>>(Wq, WqT, DMODEL, DMODEL);
  transpose_cast<<<dim3(32, 32), tb, 0, stream>>>(Wk, WkT, DMODEL, DMODEL);
  transpose_cast<<<dim3(32, 32), tb, 0, stream>>>(Wv, WvT, DMODEL, DMODEL);
  transpose_cast<<<dim3(32, 32), tb, 0, stream>>>(Wo, WoT, DMODEL, DMODEL);
  transpose_cast<<<dim3(128, 32), tb, 0, stream>>>(W1, W1T, DMODEL, DFF);
  transpose_cast<<<dim3(32, 128), tb, 0, stream>>>(W2, W2T, DFF, DMODEL);

  prep_tokens<<<(NTOK * DMODEL) / (256 * 4), 256, 0, stream>>>(src, pos, qkb, srcb);

  // QKV projections
  gemm_bt<0, 1><<<dim3(DMODEL / 128, NTOK / 128), 256, 0, stream>>>(
      qkb, WqT, bq, nullptr, Qb, NTOK, DMODEL, DMODEL);
  gemm_bt<0, 1><<<dim3(DMODEL / 128, NTOK / 128), 256, 0, stream>>>(
      qkb, WkT, bk, nullptr, Kb, NTOK, DMODEL, DMODEL);
  gemm_bt<0, 1><<<dim3(DMODEL / 128, NTOK / 128), 256, 0, stream>>>(
      srcb, WvT, bv, nullptr, Vb, NTOK, DMODEL, DMODEL);

  // attention
  attn_kernel<<<dim3(S_LEN / 64, NHEAD, BATCH), 256, 0, stream>>>(Qb, Kb, Vb, corr, ctxb);

  // output projection -> f32
  gemm_bt<0, 0><<<dim3(DMODEL / 128, NTOK / 128), 256, 0, stream>>>(
      ctxb, WoT, bo, attn_out, nullptr, NTOK, DMODEL, DMODEL);

  // LN1: x1 = LN(src + attn_out)
  residual_ln<<<NTOK, 256, 0, stream>>>(src, attn_out, g1, be1, x1f, x1b);

  // FFN
  gemm_bt<1, 1><<<dim3(DFF / 128, NTOK / 128), 256, 0, stream>>>(
      x1b, W1T, b1, nullptr, Hb, NTOK, DFF, DMODEL);
  gemm_bt<0, 0><<<dim3(DMODEL / 128, NTOK / 128), 256, 0, stream>>>(
      Hb, W2T, b2, Yf, nullptr, NTOK, DMODEL, DFF);

  // LN2 -> output
  residual_ln<<<NTOK, 256, 0, stream>>>(x1f, Yf, g2, be2, out, nullptr);
}

// Round 2
// 592.731 us; speedup vs baseline: 1.1168x; 1.1168x over previous
//
#include <hip/hip_runtime.h>
#include <hip/hip_bf16.h>

#define S_LEN  2048
#define BATCH  2
#define DMODEL 1024
#define NHEAD  16
#define DHEAD  64
#define DFF    4096
#define NTOK   (BATCH * S_LEN)

typedef __attribute__((ext_vector_type(8))) short short8;
typedef __attribute__((ext_vector_type(4))) short short4v;
typedef __attribute__((ext_vector_type(4))) float f32x4;

__device__ __forceinline__ short f2bs(float f) {
  __hip_bfloat16 h = __float2bfloat16(f);
  short s;
  __builtin_memcpy(&s, &h, sizeof(short));
  return s;
}

__device__ __forceinline__ f32x4 mfma16(short8 a, short8 b, f32x4 c) {
  return __builtin_amdgcn_mfma_f32_16x16x32_bf16(a, b, c, 0, 0, 0);
}

// ---------------------------------------------------------------------------
// Weight transpose + cast: in f32 [R][C] -> out bf16 [C][R]
// ---------------------------------------------------------------------------
__global__ void transpose_cast(const float* __restrict__ in, short* __restrict__ out,
                               int R, int C) {
  __shared__ float tile[32][33];
  const int c0 = blockIdx.x * 32, r0 = blockIdx.y * 32;
  const int tx = threadIdx.x, ty = threadIdx.y;  // 32 x 8
#pragma unroll
  for (int i = 0; i < 32; i += 8)
    tile[ty + i][tx] = in[(size_t)(r0 + ty + i) * C + c0 + tx];
  __syncthreads();
#pragma unroll
  for (int i = 0; i < 32; i += 8)
    out[(size_t)(c0 + ty + i) * R + r0 + tx] = f2bs(tile[tx][ty + i]);
}

// ---------------------------------------------------------------------------
// bf16 transpose: in [R][C] -> out [C][R], 64x64 tiles, 256 threads
// ---------------------------------------------------------------------------
__global__ __launch_bounds__(256) void transpose_bf16(
    const short* __restrict__ in, short* __restrict__ out, int R, int C) {
  __shared__ __attribute__((aligned(16))) short tile[64][72];
  const int c0 = blockIdx.x * 64, r0 = blockIdx.y * 64;
#pragma unroll
  for (int i = 0; i < 2; i++) {
    const int idx = threadIdx.x + 256 * i;
    const int rr = idx >> 3, cc8 = (idx & 7) * 8;
    *(int4*)(&tile[rr][cc8]) = *(const int4*)(in + (size_t)(r0 + rr) * C + c0 + cc8);
  }
  __syncthreads();
#pragma unroll
  for (int i = 0; i < 2; i++) {
    const int idx = threadIdx.x + 256 * i;
    const int rr = idx >> 3, cc8 = (idx & 7) * 8;  // rr: out-row (orig col), cc8: orig rows
    short8 v;
#pragma unroll
    for (int j = 0; j < 8; j++) v[j] = tile[cc8 + j][rr];
    *(short8*)(out + (size_t)(c0 + rr) * R + r0 + cc8) = v;
  }
}

// ---------------------------------------------------------------------------
// Token prep: qkb = bf16(src+pos), srcb = bf16(src)
// ---------------------------------------------------------------------------
__global__ void prep_tokens(const float* __restrict__ src, const float* __restrict__ pos,
                            short* __restrict__ qkb, short* __restrict__ srcb) {
  const int i = (blockIdx.x * blockDim.x + threadIdx.x) * 4;
  float4 s = *(const float4*)(src + i);
  float4 p = *(const float4*)(pos + i);
  short4v q4 = {f2bs(s.x + p.x), f2bs(s.y + p.y), f2bs(s.z + p.z), f2bs(s.w + p.w)};
  short4v s4 = {f2bs(s.x), f2bs(s.y), f2bs(s.z), f2bs(s.w)};
  *(short4v*)(qkb + i) = q4;
  *(short4v*)(srcb + i) = s4;
}

// ---------------------------------------------------------------------------
// GEMM: C[M][N] = (A[M][K](bf16) @ Bt[N][K](bf16)^T + bias) * scale, opt ReLU.
// 128x128 tile, BK=32, 256 threads (4 waves, each 64x64 = 4x4 MFMA tiles).
// ---------------------------------------------------------------------------
template <int RELU, int OUT_BF16>
__global__ __launch_bounds__(256) void gemm_bt(
    const short* __restrict__ A, const short* __restrict__ Bt,
    const float* __restrict__ bias, float* __restrict__ Cf, short* __restrict__ Cb,
    int M, int N, int K, float scale) {
  __shared__ __attribute__((aligned(16))) short As[128][40];
  __shared__ __attribute__((aligned(16))) short Bs[128][40];

  const int tid = threadIdx.x;
  const int wave = tid >> 6, lane = tid & 63;
  const int lm = lane & 15, lq = lane >> 4;
  const int row0 = blockIdx.y * 128, col0 = blockIdx.x * 128;
  const int wr = (wave >> 1) * 64, wc = (wave & 1) * 64;

  const int lr = tid >> 2;          // 0..63 staging row
  const int lc8 = (tid & 3) * 8;    // 0,8,16,24 staging col

  f32x4 acc[4][4];
#pragma unroll
  for (int i = 0; i < 4; i++)
#pragma unroll
    for (int j = 0; j < 4; j++) acc[i][j] = (f32x4){0.f, 0.f, 0.f, 0.f};

  for (int k0 = 0; k0 < K; k0 += 32) {
    const short* ap = A + (size_t)(row0 + lr) * K + k0 + lc8;
    *(int4*)(&As[lr][lc8]) = *(const int4*)ap;
    *(int4*)(&As[lr + 64][lc8]) = *(const int4*)(ap + (size_t)64 * K);
    const short* bp = Bt + (size_t)(col0 + lr) * K + k0 + lc8;
    *(int4*)(&Bs[lr][lc8]) = *(const int4*)bp;
    *(int4*)(&Bs[lr + 64][lc8]) = *(const int4*)(bp + (size_t)64 * K);
    __syncthreads();

    short8 af[4], bfr[4];
#pragma unroll
    for (int i = 0; i < 4; i++) af[i] = *(const short8*)(&As[wr + 16 * i + lm][lq * 8]);
#pragma unroll
    for (int j = 0; j < 4; j++) bfr[j] = *(const short8*)(&Bs[wc + 16 * j + lm][lq * 8]);
#pragma unroll
    for (int i = 0; i < 4; i++)
#pragma unroll
      for (int j = 0; j < 4; j++) acc[i][j] = mfma16(af[i], bfr[j], acc[i][j]);
    __syncthreads();
  }

#pragma unroll
  for (int i = 0; i < 4; i++) {
#pragma unroll
    for (int j = 0; j < 4; j++) {
      const int col = col0 + wc + 16 * j + lm;
      const float bs = bias[col];
#pragma unroll
      for (int r = 0; r < 4; r++) {
        const int row = row0 + wr + 16 * i + lq * 4 + r;
        float v = (acc[i][j][r] + bs) * scale;
        if (RELU) v = fmaxf(v, 0.f);
        if (OUT_BF16)
          Cb[(size_t)row * N + col] = f2bs(v);
        else
          Cf[(size_t)row * N + col] = v;
      }
    }
  }
}

// ---------------------------------------------------------------------------
// Fused attention, S^T formulation. Block = (head h, 64-query tile, batch b),
// 4 waves x 16 queries. Per 64-key iteration:
//   S^T[key][q] = mfma(a=K[key][d], b=Q[q][d])  (Q pre-scaled by 1/8)
//   softmax across keys = across regs + 2 quad-shuffles (m,l,alpha lane-scalar)
//   O^T[d][q] += mfma(a=VT[d][key], b=P[q][key])  (P via LDS b64/b128 roundtrip)
// ---------------------------------------------------------------------------
__global__ __launch_bounds__(256) void attn_kernel(
    const short* __restrict__ Q, const short* __restrict__ K,
    const short* __restrict__ VT, const float* __restrict__ corr,
    short* __restrict__ ctx) {
  const int h = blockIdx.x, qtile = blockIdx.y, b = blockIdx.z;
  const int tid = threadIdx.x;
  const int wave = tid >> 6, lane = tid & 63;
  const int lm = lane & 15, lq = lane >> 4;
  const int qloc = qtile * 64 + wave * 16 + lm;    // this lane's query (0..2047)

  __shared__ __attribute__((aligned(16))) short Ks[64][72];      // [key][d]
  __shared__ __attribute__((aligned(16))) short Vs[64][72];      // [d][key]
  __shared__ __attribute__((aligned(16))) short Ps[4][16][72];   // per-wave [q][key]

  // Q b-fragments: b[n=q=lm][k=d=lq*8+j (+32)]
  const short* qrow = Q + (size_t)(b * S_LEN + qloc) * DMODEL + h * DHEAD;
  const short8 qb0 = *(const short8*)(qrow + lq * 8);
  const short8 qb1 = *(const short8*)(qrow + lq * 8 + 32);

  f32x4 o[4];  // o[t] = O^T[d = t*16 + lq*4 + r][q = lm]
#pragma unroll
  for (int t = 0; t < 4; t++) o[t] = (f32x4){0.f, 0.f, 0.f, 0.f};
  float m = -1e30f, l = 0.f;

  const short* Kb = K + (size_t)(b * S_LEN) * DMODEL + h * DHEAD;
  const short* Vb = VT + (size_t)(h * DHEAD) * NTOK + b * S_LEN;
  const float* cp = corr + ((size_t)b * S_LEN + qloc) * S_LEN;

  const int srow = tid >> 3;         // 0..31 (then +32 for second half)
  const int sc8 = (tid & 7) * 8;     // staging chunk

  for (int kt = 0; kt < S_LEN; kt += 64) {
    // --- stage K tile [64 key][64 d] and VT tile [64 d][64 key], int4 coalesced
#pragma unroll
    for (int i = 0; i < 2; i++) {
      const int rr = srow + 32 * i;
      *(int4*)(&Ks[rr][sc8]) = *(const int4*)(Kb + (size_t)(kt + rr) * DMODEL + sc8);
      *(int4*)(&Vs[rr][sc8]) = *(const int4*)(Vb + (size_t)rr * NTOK + kt + sc8);
    }
    __syncthreads();

    // --- scores S^T: 4 key-16-tiles, k over 64 dims (2 MFMAs each)
    f32x4 sv[4];
#pragma unroll
    for (int t = 0; t < 4; t++) {
      const short8 kf0 = *(const short8*)(&Ks[t * 16 + lm][lq * 8]);
      const short8 kf1 = *(const short8*)(&Ks[t * 16 + lm][lq * 8 + 32]);
      f32x4 a = (f32x4){0.f, 0.f, 0.f, 0.f};
      a = mfma16(kf0, qb0, a);
      a = mfma16(kf1, qb1, a);
      sv[t] = a;
    }

    // --- corr bias (float4 per tile) + online softmax across keys
#pragma unroll
    for (int t = 0; t < 4; t++) {
      const f32x4 cv = *(const f32x4*)(cp + kt + t * 16 + lq * 4);
      sv[t] += cv;
    }
    float mx = -1e30f;
#pragma unroll
    for (int t = 0; t < 4; t++) {
      mx = fmaxf(mx, fmaxf(fmaxf(sv[t][0], sv[t][1]), fmaxf(sv[t][2], sv[t][3])));
    }
    mx = fmaxf(mx, __shfl_xor(mx, 16));
    mx = fmaxf(mx, __shfl_xor(mx, 32));
    const float mn = fmaxf(m, mx);
    const float alpha = __expf(m - mn);
    m = mn;
    float rs = 0.f;
#pragma unroll
    for (int t = 0; t < 4; t++) {
#pragma unroll
      for (int r = 0; r < 4; r++) {
        const float p = __expf(sv[t][r] - mn);
        sv[t][r] = p;
        rs += p;
      }
    }
    rs += __shfl_xor(rs, 16);
    rs += __shfl_xor(rs, 32);
    l = l * alpha + rs;
#pragma unroll
    for (int t = 0; t < 4; t++) o[t] *= alpha;

    // --- P to LDS (vectorized b64 writes), wave-private so no barrier needed
#pragma unroll
    for (int t = 0; t < 4; t++) {
      short4v pk = {f2bs(sv[t][0]), f2bs(sv[t][1]), f2bs(sv[t][2]), f2bs(sv[t][3])};
      *(short4v*)(&Ps[wave][lm][t * 16 + lq * 4]) = pk;
    }

    // --- PV: O^T[d][q] += VT-tile . P  (k = 2 chunks of 32 keys)
    const short8 pf0 = *(const short8*)(&Ps[wave][lm][lq * 8]);
    const short8 pf1 = *(const short8*)(&Ps[wave][lm][32 + lq * 8]);
#pragma unroll
    for (int t = 0; t < 4; t++) {
      const short8 vf0 = *(const short8*)(&Vs[t * 16 + lm][lq * 8]);
      const short8 vf1 = *(const short8*)(&Vs[t * 16 + lm][32 + lq * 8]);
      o[t] = mfma16(vf0, pf0, o[t]);
      o[t] = mfma16(vf1, pf1, o[t]);
    }
    __syncthreads();
  }

  // --- epilogue: O/l, ctx[token][h*64+d], vectorized 4-short stores
  const float inv = 1.0f / l;
  short* op = ctx + (size_t)(b * S_LEN + qloc) * DMODEL + h * DHEAD;
#pragma unroll
  for (int t = 0; t < 4; t++) {
    short4v ov = {f2bs(o[t][0] * inv), f2bs(o[t][1] * inv),
                  f2bs(o[t][2] * inv), f2bs(o[t][3] * inv)};
    *(short4v*)(op + t * 16 + lq * 4) = ov;
  }
}

// ---------------------------------------------------------------------------
// Residual + LayerNorm over 1024 dims. One block (256 thr) per token row.
// ---------------------------------------------------------------------------
__global__ __launch_bounds__(256) void residual_ln(
    const float* __restrict__ xa, const float* __restrict__ xb,
    const float* __restrict__ g, const float* __restrict__ be,
    float* __restrict__ outf, short* __restrict__ outb) {
  const int row = blockIdx.x;
  const int t = threadIdx.x;
  const size_t base = (size_t)row * DMODEL + t * 4;
  float4 a = *(const float4*)(xa + base);
  float4 b = *(const float4*)(xb + base);
  const float v0 = a.x + b.x, v1 = a.y + b.y, v2 = a.z + b.z, v3 = a.w + b.w;
  float sum = v0 + v1 + v2 + v3;
  float sq = v0 * v0 + v1 * v1 + v2 * v2 + v3 * v3;
#pragma unroll
  for (int off = 1; off < 64; off <<= 1) {
    sum += __shfl_xor(sum, off);
    sq += __shfl_xor(sq, off);
  }
  __shared__ float ssum[4], ssq[4];
  const int wave = t >> 6;
  if ((t & 63) == 0) { ssum[wave] = sum; ssq[wave] = sq; }
  __syncthreads();
  sum = ssum[0] + ssum[1] + ssum[2] + ssum[3];
  sq = ssq[0] + ssq[1] + ssq[2] + ssq[3];
  const float mean = sum * (1.0f / DMODEL);
  const float var = sq * (1.0f / DMODEL) - mean * mean;
  const float rstd = rsqrtf(var + 1e-5f);
  float4 gv = *(const float4*)(g + t * 4);
  float4 bv = *(const float4*)(be + t * 4);
  const float o0 = (v0 - mean) * rstd * gv.x + bv.x;
  const float o1 = (v1 - mean) * rstd * gv.y + bv.y;
  const float o2 = (v2 - mean) * rstd * gv.z + bv.z;
  const float o3 = (v3 - mean) * rstd * gv.w + bv.w;
  if (outf) {
    float4 ov = {o0, o1, o2, o3};
    *(float4*)(outf + base) = ov;
  }
  if (outb) {
    short4v ob = {f2bs(o0), f2bs(o1), f2bs(o2), f2bs(o3)};
    *(short4v*)(outb + base) = ob;
  }
}

// ---------------------------------------------------------------------------
extern "C" void kernel_launch(void* const* d_in, const int* in_sizes, int n_in,
                              void* d_out, int out_size, void* d_ws, size_t ws_size,
                              hipStream_t stream) {
  const float* src = (const float*)d_in[0];
  const float* corr = (const float*)d_in[1];
  const float* pos = (const float*)d_in[2];
  const float* Wq = (const float*)d_in[3];
  const float* bq = (const float*)d_in[4];
  const float* Wk = (const float*)d_in[5];
  const float* bk = (const float*)d_in[6];
  const float* Wv = (const float*)d_in[7];
  const float* bv = (const float*)d_in[8];
  const float* Wo = (const float*)d_in[9];
  const float* bo = (const float*)d_in[10];
  const float* W1 = (const float*)d_in[11];
  const float* b1 = (const float*)d_in[12];
  const float* W2 = (const float*)d_in[13];
  const float* b2 = (const float*)d_in[14];
  const float* g1 = (const float*)d_in[15];
  const float* be1 = (const float*)d_in[16];
  const float* g2 = (const float*)d_in[17];
  const float* be2 = (const float*)d_in[18];
  float* out = (float*)d_out;

  char* ws = (char*)d_ws;
  size_t off = 0;
  auto alloc = [&](size_t bytes) {
    char* p = ws + off;
    off += (bytes + 255) & ~(size_t)255;
    return p;
  };
  short* WqT = (short*)alloc((size_t)DMODEL * DMODEL * 2);
  short* WkT = (short*)alloc((size_t)DMODEL * DMODEL * 2);
  short* WvT = (short*)alloc((size_t)DMODEL * DMODEL * 2);
  short* WoT = (short*)alloc((size_t)DMODEL * DMODEL * 2);
  short* W1T = (short*)alloc((size_t)DFF * DMODEL * 2);    // [4096][1024]
  short* W2T = (short*)alloc((size_t)DMODEL * DFF * 2);    // [1024][4096]
  short* qkb = (short*)alloc((size_t)NTOK * DMODEL * 2);
  short* srcb = (short*)alloc((size_t)NTOK * DMODEL * 2);
  short* Qb = (short*)alloc((size_t)NTOK * DMODEL * 2);
  short* Kb = (short*)alloc((size_t)NTOK * DMODEL * 2);
  short* Vb = (short*)alloc((size_t)NTOK * DMODEL * 2);
  short* VTt = (short*)alloc((size_t)DMODEL * NTOK * 2);   // [1024][4096]
  short* ctxb = (short*)alloc((size_t)NTOK * DMODEL * 2);
  float* attn_out = (float*)alloc((size_t)NTOK * DMODEL * 4);
  float* x1f = (float*)alloc((size_t)NTOK * DMODEL * 4);
  short* x1b = (short*)alloc((size_t)NTOK * DMODEL * 2);
  short* Hb = (short*)alloc((size_t)NTOK * DFF * 2);
  float* Yf = (float*)alloc((size_t)NTOK * DMODEL * 4);

  const dim3 tb(32, 8);
  transpose_cast<<<dim3(32, 32), tb, 0, stream>>>(Wq, WqT, DMODEL, DMODEL);
  transpose_cast<<<dim3(32, 32), tb, 0, stream>>>(Wk, WkT, DMODEL, DMODEL);
  transpose_cast<<<dim3(32, 32), tb, 0, stream>>>(Wv, WvT, DMODEL, DMODEL);
  transpose_cast<<<dim3(32, 32), tb, 0, stream>>>(Wo, WoT, DMODEL, DMODEL);
  transpose_cast<<<dim3(128, 32), tb, 0, stream>>>(W1, W1T, DMODEL, DFF);
  transpose_cast<<<dim3(32, 128), tb, 0, stream>>>(W2, W2T, DFF, DMODEL);

  prep_tokens<<<(NTOK * DMODEL) / (256 * 4), 256, 0, stream>>>(src, pos, qkb, srcb);

  // QKV projections (Q scaled by 1/sqrt(d_k) = 0.125 in-epilogue)
  gemm_bt<0, 1><<<dim3(DMODEL / 128, NTOK / 128), 256, 0, stream>>>(
      qkb, WqT, bq, nullptr, Qb, NTOK, DMODEL, DMODEL, 0.125f);
  gemm_bt<0, 1><<<dim3(DMODEL / 128, NTOK / 128), 256, 0, stream>>>(
      qkb, WkT, bk, nullptr, Kb, NTOK, DMODEL, DMODEL, 1.0f);
  gemm_bt<0, 1><<<dim3(DMODEL / 128, NTOK / 128), 256, 0, stream>>>(
      srcb, WvT, bv, nullptr, Vb, NTOK, DMODEL, DMODEL, 1.0f);

  // V^T for attention PV a-operand: [NTOK][DMODEL] -> [DMODEL][NTOK]
  transpose_bf16<<<dim3(DMODEL / 64, NTOK / 64), 256, 0, stream>>>(Vb, VTt, NTOK, DMODEL);

  // attention
  attn_kernel<<<dim3(NHEAD, S_LEN / 64, BATCH), 256, 0, stream>>>(Qb, Kb, VTt, corr, ctxb);

  // output projection -> f32
  gemm_bt<0, 0><<<dim3(DMODEL / 128, NTOK / 128), 256, 0, stream>>>(
      ctxb, WoT, bo, attn_out, nullptr, NTOK, DMODEL, DMODEL, 1.0f);

  // LN1: x1 = LN(src + attn_out)
  residual_ln<<<NTOK, 256, 0, stream>>>(src, attn_out, g1, be1, x1f, x1b);

  // FFN
  gemm_bt<1, 1><<<dim3(DFF / 128, NTOK / 128), 256, 0, stream>>>(
      x1b, W1T, b1, nullptr, Hb, NTOK, DFF, DMODEL, 1.0f);
  gemm_bt<0, 0><<<dim3(DMODEL / 128, NTOK / 128), 256, 0, stream>>>(
      Hb, W2T, b2, Yf, nullptr, NTOK, DMODEL, DFF, 1.0f);

  // LN2 -> output
  residual_ln<<<NTOK, 256, 0, stream>>>(x1f, Yf, g2, be2, out, nullptr);
}